// Round 1
// baseline (1268.595 us; speedup 1.0000x reference)
//
#include <hip/hip_runtime.h>

#define T_TOK 2048
#define TOPK  8
#define NEXP  32
#define HDIM  1024
#define IDIM  768
#define NPAIR (T_TOK * TOPK)   // 16384
#define BM 128
#define BN 128
#define BK 32
#define MT_MAX (NPAIR / BM + NEXP)  // 160 upper bound on sum(ceil(Me/BM))

typedef __attribute__((ext_vector_type(8))) short short8;   // 8 x bf16 (4 VGPRs)
typedef __attribute__((ext_vector_type(4))) float f32x4;    // MFMA accumulator

__device__ __forceinline__ unsigned short f2bf(float f) {
    // round-to-nearest-even fp32 -> bf16 (inputs are finite)
    unsigned x = __float_as_uint(f);
    unsigned r = x + 0x7fffu + ((x >> 16) & 1u);
    return (unsigned short)(r >> 16);
}
__device__ __forceinline__ float bf2f(unsigned short u) {
    return __uint_as_float(((unsigned)u) << 16);
}
__device__ __forceinline__ short8 pack8(float4 a, float4 b) {
    short8 v;
    v[0] = (short)f2bf(a.x); v[1] = (short)f2bf(a.y);
    v[2] = (short)f2bf(a.z); v[3] = (short)f2bf(a.w);
    v[4] = (short)f2bf(b.x); v[5] = (short)f2bf(b.y);
    v[6] = (short)f2bf(b.z); v[7] = (short)f2bf(b.w);
    return v;
}

// ---------------- routing kernels ----------------
__global__ void k_init(int* counts) {
    if (threadIdx.x < NEXP) counts[threadIdx.x] = 0;
}

__global__ void k_hist(const int* __restrict__ idx, int* __restrict__ counts) {
    int p = blockIdx.x * 256 + threadIdx.x;
    atomicAdd(&counts[idx[p]], 1);
}

__global__ void k_scan(const int* __restrict__ counts, int* __restrict__ offsets,
                       int* __restrict__ mtb, int* __restrict__ cursor) {
    if (threadIdx.x == 0) {
        int tot = 0, mt = 0;
        for (int e = 0; e < NEXP; ++e) {
            offsets[e] = tot; mtb[e] = mt;
            tot += counts[e];
            mt += (counts[e] + BM - 1) / BM;
        }
        offsets[NEXP] = tot; mtb[NEXP] = mt;
    }
    if (threadIdx.x < NEXP) cursor[threadIdx.x] = 0;
}

__global__ void k_scatter(const int* __restrict__ idx, int* __restrict__ cursor,
                          const int* __restrict__ offsets, int* __restrict__ pair_token,
                          int* __restrict__ pair_slot) {
    int p = blockIdx.x * 256 + threadIdx.x;
    int e = idx[p];
    int pos = atomicAdd(&cursor[e], 1);
    int slot = offsets[e] + pos;
    pair_token[slot] = p >> 3;   // p / TOPK
    pair_slot[p] = slot;
}

// LDS fragment-contiguous index: 16B chunk for (row m, k-chunk c)
__device__ __forceinline__ int idx16(int m, int c) {
    return ((m >> 4) * 4 + c) * 16 + (m & 15);
}

// ---------------- gate+up fused GEMM + SwiGLU ----------------
// h_mid[pair, n] = silu(x . gate_e[n]) * (x . up_e[n]),  bf16 out
__global__ __launch_bounds__(256) void k_gateup(
    const float* __restrict__ hidden, const float* __restrict__ gate,
    const float* __restrict__ up, const int* __restrict__ pair_token,
    const int* __restrict__ offsets, const int* __restrict__ mtb,
    unsigned short* __restrict__ h_mid)
{
    __shared__ short8 sA[512], sBg[512], sBu[512];
    __shared__ int sInfo[4];
    int tid = threadIdx.x;
    if (tid == 0) {
        int mt = blockIdx.x;
        if (mt >= mtb[NEXP]) { sInfo[0] = -1; }
        else {
            int e = 0;
            while (mtb[e + 1] <= mt) e++;
            sInfo[0] = e; sInfo[1] = offsets[e];
            sInfo[2] = offsets[e + 1] - offsets[e];
            sInfo[3] = (mt - mtb[e]) * BM;
        }
    }
    __syncthreads();
    int e = sInfo[0];
    if (e < 0) return;
    int off = sInfo[1], Me = sInfo[2], mrow0 = sInfo[3];
    int n0 = blockIdx.y * BN;

    // staging: thread -> (row hm in tile, half of BK)
    int hm = tid >> 1, half = tid & 1;
    int rowp = mrow0 + hm;
    int tok = (rowp < Me) ? pair_token[off + rowp] : 0;
    const float4* aSrc = (const float4*)(hidden + (size_t)tok * HDIM);
    const float4* gSrc = (const float4*)(gate + ((size_t)e * IDIM + (n0 + hm)) * HDIM);
    const float4* uSrc = (const float4*)(up   + ((size_t)e * IDIM + (n0 + hm)) * HDIM);
    int w0 = idx16(hm, half * 2);
    int w1 = w0 + 16;

    // compute: wave -> 64x64 quadrant, 4x4 frags of 16x16
    int wave = tid >> 6, lane = tid & 63, quad = lane >> 4, l16 = lane & 15;
    int wm = (wave & 1) * 64, wn = (wave >> 1) * 64;
    int aBase = ((wm >> 4) * 4 + quad) * 16 + l16;
    int bBase = ((wn >> 4) * 4 + quad) * 16 + l16;

    f32x4 zero = {0.f, 0.f, 0.f, 0.f};
    f32x4 accg[4][4], accu[4][4];
    for (int i = 0; i < 4; ++i)
        for (int j = 0; j < 4; ++j) { accg[i][j] = zero; accu[i][j] = zero; }

    for (int k0 = 0; k0 < HDIM; k0 += BK) {
        int base = (k0 >> 2) + (half << 2);
        float4 a0 = aSrc[base], a1 = aSrc[base + 1], a2 = aSrc[base + 2], a3 = aSrc[base + 3];
        float4 g0 = gSrc[base], g1 = gSrc[base + 1], g2 = gSrc[base + 2], g3 = gSrc[base + 3];
        float4 u0 = uSrc[base], u1 = uSrc[base + 1], u2 = uSrc[base + 2], u3 = uSrc[base + 3];
        __syncthreads();
        sA[w0] = pack8(a0, a1);  sA[w1] = pack8(a2, a3);
        sBg[w0] = pack8(g0, g1); sBg[w1] = pack8(g2, g3);
        sBu[w0] = pack8(u0, u1); sBu[w1] = pack8(u2, u3);
        __syncthreads();
        short8 af[4];
        for (int fm = 0; fm < 4; ++fm) af[fm] = sA[aBase + fm * 64];
        for (int fn = 0; fn < 4; ++fn) {
            short8 bg = sBg[bBase + fn * 64];
            short8 bu = sBu[bBase + fn * 64];
            for (int fm = 0; fm < 4; ++fm) {
                accg[fm][fn] = __builtin_amdgcn_mfma_f32_16x16x32_bf16(af[fm], bg, accg[fm][fn], 0, 0, 0);
                accu[fm][fn] = __builtin_amdgcn_mfma_f32_16x16x32_bf16(af[fm], bu, accu[fm][fn], 0, 0, 0);
            }
        }
    }

    // epilogue: silu(g)*u -> bf16 h_mid   (C/D: row=(lane>>4)*4+reg, col=lane&15)
    for (int fm = 0; fm < 4; ++fm)
        for (int fn = 0; fn < 4; ++fn)
            for (int r = 0; r < 4; ++r) {
                int mloc = wm + fm * 16 + quad * 4 + r;
                int prow = mrow0 + mloc;
                if (prow < Me) {
                    int col = n0 + wn + fn * 16 + l16;
                    float g = accg[fm][fn][r], u = accu[fm][fn][r];
                    float h = g / (1.f + __expf(-g)) * u;
                    h_mid[(size_t)(off + prow) * IDIM + col] = f2bf(h);
                }
            }
}

// ---------------- down GEMM ----------------
// y_pair[pair, n] = h_mid[pair] . down_e[n],  bf16 out (weight applied in reduce)
__global__ __launch_bounds__(256) void k_down(
    const unsigned short* __restrict__ h_mid, const float* __restrict__ down,
    const int* __restrict__ offsets, const int* __restrict__ mtb,
    unsigned short* __restrict__ y_pair)
{
    __shared__ short8 sA[512], sB[512];
    __shared__ int sInfo[4];
    int tid = threadIdx.x;
    if (tid == 0) {
        int mt = blockIdx.x;
        if (mt >= mtb[NEXP]) { sInfo[0] = -1; }
        else {
            int e = 0;
            while (mtb[e + 1] <= mt) e++;
            sInfo[0] = e; sInfo[1] = offsets[e];
            sInfo[2] = offsets[e + 1] - offsets[e];
            sInfo[3] = (mt - mtb[e]) * BM;
        }
    }
    __syncthreads();
    int e = sInfo[0];
    if (e < 0) return;
    int off = sInfo[1], Me = sInfo[2], mrow0 = sInfo[3];
    int n0 = blockIdx.y * BN;

    int hm = tid >> 1, half = tid & 1;
    int rowp = mrow0 + hm;
    int arow = off + ((rowp < Me) ? rowp : 0);
    const short8* aSrc = (const short8*)(h_mid + (size_t)arow * IDIM);
    const float4* bSrc = (const float4*)(down + ((size_t)e * HDIM + (n0 + hm)) * IDIM);
    int w0 = idx16(hm, half * 2);
    int w1 = w0 + 16;

    int wave = tid >> 6, lane = tid & 63, quad = lane >> 4, l16 = lane & 15;
    int wm = (wave & 1) * 64, wn = (wave >> 1) * 64;
    int aBase = ((wm >> 4) * 4 + quad) * 16 + l16;
    int bBase = ((wn >> 4) * 4 + quad) * 16 + l16;

    f32x4 zero = {0.f, 0.f, 0.f, 0.f};
    f32x4 acc[4][4];
    for (int i = 0; i < 4; ++i)
        for (int j = 0; j < 4; ++j) acc[i][j] = zero;

    for (int k0 = 0; k0 < IDIM; k0 += BK) {
        int abase = (k0 >> 3) + (half << 1);
        short8 A0 = aSrc[abase], A1 = aSrc[abase + 1];
        int bbase = (k0 >> 2) + (half << 2);
        float4 b0 = bSrc[bbase], b1 = bSrc[bbase + 1], b2 = bSrc[bbase + 2], b3 = bSrc[bbase + 3];
        __syncthreads();
        sA[w0] = A0; sA[w1] = A1;
        sB[w0] = pack8(b0, b1); sB[w1] = pack8(b2, b3);
        __syncthreads();
        short8 af[4];
        for (int fm = 0; fm < 4; ++fm) af[fm] = sA[aBase + fm * 64];
        for (int fn = 0; fn < 4; ++fn) {
            short8 bf = sB[bBase + fn * 64];
            for (int fm = 0; fm < 4; ++fm)
                acc[fm][fn] = __builtin_amdgcn_mfma_f32_16x16x32_bf16(af[fm], bf, acc[fm][fn], 0, 0, 0);
        }
    }

    for (int fm = 0; fm < 4; ++fm)
        for (int fn = 0; fn < 4; ++fn)
            for (int r = 0; r < 4; ++r) {
                int mloc = wm + fm * 16 + quad * 4 + r;
                int prow = mrow0 + mloc;
                if (prow < Me) {
                    int col = n0 + wn + fn * 16 + l16;
                    y_pair[(size_t)(off + prow) * HDIM + col] = f2bf(acc[fm][fn][r]);
                }
            }
}

// ---------------- per-token weighted reduce ----------------
__global__ void k_reduce(const unsigned short* __restrict__ y_pair,
                         const int* __restrict__ pair_slot,
                         const float* __restrict__ topw, float* __restrict__ out)
{
    int t = blockIdx.x;
    __shared__ int ss[TOPK];
    __shared__ float sw[TOPK];
    if (threadIdx.x < TOPK) {
        ss[threadIdx.x] = pair_slot[t * TOPK + threadIdx.x];
        sw[threadIdx.x] = topw[t * TOPK + threadIdx.x];
    }
    __syncthreads();
    int c = threadIdx.x * 4;
    float a0 = 0.f, a1 = 0.f, a2 = 0.f, a3 = 0.f;
    for (int k = 0; k < TOPK; ++k) {
        const unsigned short* yr = y_pair + (size_t)ss[k] * HDIM + c;
        uint2 v = *(const uint2*)yr;
        float w = sw[k];
        a0 += w * bf2f((unsigned short)(v.x & 0xffff));
        a1 += w * bf2f((unsigned short)(v.x >> 16));
        a2 += w * bf2f((unsigned short)(v.y & 0xffff));
        a3 += w * bf2f((unsigned short)(v.y >> 16));
    }
    float4 o = {a0, a1, a2, a3};
    *(float4*)(out + (size_t)t * HDIM + c) = o;
}

extern "C" void kernel_launch(void* const* d_in, const int* in_sizes, int n_in,
                              void* d_out, int out_size, void* d_ws, size_t ws_size,
                              hipStream_t stream) {
    (void)in_sizes; (void)n_in; (void)out_size; (void)ws_size;
    const float* hidden = (const float*)d_in[0];
    const int*   tki    = (const int*)d_in[1];
    const float* tkw    = (const float*)d_in[2];
    const float* gate   = (const float*)d_in[3];
    const float* up     = (const float*)d_in[4];
    const float* down   = (const float*)d_in[5];
    float* out = (float*)d_out;

    char* w = (char*)d_ws;
    unsigned short* h_mid  = (unsigned short*)w;                                   // NPAIR*IDIM bf16 = 25.2 MB
    unsigned short* y_pair = (unsigned short*)(w + (size_t)NPAIR * IDIM * 2);      // NPAIR*HDIM bf16 = 33.6 MB
    int* ib = (int*)(w + (size_t)NPAIR * IDIM * 2 + (size_t)NPAIR * HDIM * 2);
    int* pair_token = ib;                // NPAIR
    int* pair_slot  = ib + NPAIR;        // NPAIR
    int* counts     = ib + 2 * NPAIR;    // NEXP
    int* cursor     = counts + NEXP;     // NEXP
    int* offsets    = cursor + NEXP;     // NEXP+1
    int* mtb        = offsets + NEXP + 1;// NEXP+1

    k_init<<<1, 64, 0, stream>>>(counts);
    k_hist<<<NPAIR / 256, 256, 0, stream>>>(tki, counts);
    k_scan<<<1, 64, 0, stream>>>(counts, offsets, mtb, cursor);
    k_scatter<<<NPAIR / 256, 256, 0, stream>>>(tki, cursor, offsets, pair_token, pair_slot);
    k_gateup<<<dim3(MT_MAX, IDIM / BN), 256, 0, stream>>>(hidden, gate, up, pair_token, offsets, mtb, h_mid);
    k_down<<<dim3(MT_MAX, HDIM / BN), 256, 0, stream>>>(h_mid, down, offsets, mtb, y_pair);
    k_reduce<<<T_TOK, 256, 0, stream>>>(y_pair, pair_slot, tkw, out);
}

// Round 2
// 580.320 us; speedup vs baseline: 2.1860x; 2.1860x over previous
//
#include <hip/hip_runtime.h>

#define T_TOK 2048
#define TOPK  8
#define NEXP  32
#define HDIM  1024
#define IDIM  768
#define NPAIR (T_TOK * TOPK)   // 16384
#define BM 128
#define BK 32
#define MT_MAX (NPAIR / BM + NEXP)  // 160 upper bound on sum(ceil(Me/BM))

typedef __attribute__((ext_vector_type(8))) short short8;   // 8 x bf16 (4 VGPRs)
typedef __attribute__((ext_vector_type(4))) float f32x4;    // MFMA accumulator

__device__ __forceinline__ unsigned short f2bf(float f) {
    unsigned x = __float_as_uint(f);
    unsigned r = x + 0x7fffu + ((x >> 16) & 1u);
    return (unsigned short)(r >> 16);
}
__device__ __forceinline__ float bf2f(unsigned short u) {
    return __uint_as_float(((unsigned)u) << 16);
}
__device__ __forceinline__ short8 pack8(float4 a, float4 b) {
    short8 v;
    v[0] = (short)f2bf(a.x); v[1] = (short)f2bf(a.y);
    v[2] = (short)f2bf(a.z); v[3] = (short)f2bf(a.w);
    v[4] = (short)f2bf(b.x); v[5] = (short)f2bf(b.y);
    v[6] = (short)f2bf(b.z); v[7] = (short)f2bf(b.w);
    return v;
}

// ---------------- routing kernels ----------------
__global__ void k_init(int* counts) {
    if (threadIdx.x < NEXP) counts[threadIdx.x] = 0;
}

__global__ void k_hist(const int* __restrict__ idx, int* __restrict__ counts) {
    int p = blockIdx.x * 256 + threadIdx.x;
    atomicAdd(&counts[idx[p]], 1);
}

__global__ void k_scan(const int* __restrict__ counts, int* __restrict__ offsets,
                       int* __restrict__ mtb, int* __restrict__ cursor) {
    if (threadIdx.x == 0) {
        int tot = 0, mt = 0;
        for (int e = 0; e < NEXP; ++e) {
            offsets[e] = tot; mtb[e] = mt;
            tot += counts[e];
            mt += (counts[e] + BM - 1) / BM;
        }
        offsets[NEXP] = tot; mtb[NEXP] = mt;
    }
    if (threadIdx.x < NEXP) cursor[threadIdx.x] = 0;
}

__global__ void k_scatter(const int* __restrict__ idx, int* __restrict__ cursor,
                          const int* __restrict__ offsets, int* __restrict__ pair_token,
                          int* __restrict__ pair_slot) {
    int p = blockIdx.x * 256 + threadIdx.x;
    int e = idx[p];
    int pos = atomicAdd(&cursor[e], 1);
    int slot = offsets[e] + pos;
    pair_token[slot] = p >> 3;   // p / TOPK
    pair_slot[p] = slot;
}

// LDS fragment-contiguous index: 16B chunk for (row m, k-chunk c), c in [0,4)
__device__ __forceinline__ int idx16(int m, int c) {
    return ((m >> 4) * 4 + c) * 16 + (m & 15);
}

// ---------------- gate+up fused GEMM + SwiGLU ----------------
// BN = 64 here: 2x(128x64) fp32 acc = 64 regs/thread -> no spill.
// h_mid[pair, n] = silu(x . gate_e[n]) * (x . up_e[n]),  bf16 out
__global__ __launch_bounds__(256, 2) void k_gateup(
    const float* __restrict__ hidden, const float* __restrict__ gate,
    const float* __restrict__ up, const int* __restrict__ pair_token,
    const int* __restrict__ offsets, const int* __restrict__ mtb,
    unsigned short* __restrict__ h_mid)
{
    __shared__ short8 sA[512], sBg[256], sBu[256];
    __shared__ int sInfo[4];
    int tid = threadIdx.x;
    if (tid == 0) {
        int mt = blockIdx.x;
        if (mt >= mtb[NEXP]) { sInfo[0] = -1; }
        else {
            int e = 0;
            while (mtb[e + 1] <= mt) e++;
            sInfo[0] = e; sInfo[1] = offsets[e];
            sInfo[2] = offsets[e + 1] - offsets[e];
            sInfo[3] = (mt - mtb[e]) * BM;
        }
    }
    __syncthreads();
    int e = sInfo[0];
    if (e < 0) return;
    int off = sInfo[1], Me = sInfo[2], mrow0 = sInfo[3];
    int n0 = blockIdx.y * 64;

    // A staging: thread -> (row hm of 128, half of BK); 4 float4 each
    int hm = tid >> 1, half = tid & 1;
    int rowp = mrow0 + hm;
    int tok = (rowp < Me) ? pair_token[off + rowp] : 0;
    const float4* aSrc = (const float4*)(hidden + (size_t)tok * HDIM);
    int wA0 = idx16(hm, half * 2);
    int wA1 = wA0 + 16;

    // B staging: thread -> (row bhm of 64, quarter q of BK); 2 float4 each per tensor
    int bhm = tid >> 2, q = tid & 3;
    const float4* gSrc = (const float4*)(gate + ((size_t)e * IDIM + (n0 + bhm)) * HDIM);
    const float4* uSrc = (const float4*)(up   + ((size_t)e * IDIM + (n0 + bhm)) * HDIM);
    int wB = idx16(bhm, q);

    // compute: 4 waves in 2x2; wave tile 64(m) x 32(n); frags 4(m) x 2(n)
    int wave = tid >> 6, lane = tid & 63, quad = lane >> 4, l16 = lane & 15;
    int wm = (wave & 1) * 64, wn = (wave >> 1) * 32;
    int aBase = ((wm >> 4) * 4 + quad) * 16 + l16;
    int bBase = ((wn >> 4) * 4 + quad) * 16 + l16;

    f32x4 zero = {0.f, 0.f, 0.f, 0.f};
    f32x4 accg[4][2], accu[4][2];
#pragma unroll
    for (int i = 0; i < 4; ++i)
#pragma unroll
        for (int j = 0; j < 2; ++j) { accg[i][j] = zero; accu[i][j] = zero; }

    for (int k0 = 0; k0 < HDIM; k0 += BK) {
        int abase = (k0 >> 2) + (half << 2);
        float4 a0 = aSrc[abase], a1 = aSrc[abase + 1], a2 = aSrc[abase + 2], a3 = aSrc[abase + 3];
        int bbase = (k0 >> 2) + (q << 1);
        float4 g0 = gSrc[bbase], g1 = gSrc[bbase + 1];
        float4 u0 = uSrc[bbase], u1 = uSrc[bbase + 1];
        __syncthreads();
        sA[wA0] = pack8(a0, a1); sA[wA1] = pack8(a2, a3);
        sBg[wB] = pack8(g0, g1);
        sBu[wB] = pack8(u0, u1);
        __syncthreads();
        short8 af[4];
#pragma unroll
        for (int fm = 0; fm < 4; ++fm) af[fm] = sA[aBase + fm * 64];
#pragma unroll
        for (int fn = 0; fn < 2; ++fn) {
            short8 bg = sBg[bBase + fn * 64];
            short8 bu = sBu[bBase + fn * 64];
#pragma unroll
            for (int fm = 0; fm < 4; ++fm) {
                accg[fm][fn] = __builtin_amdgcn_mfma_f32_16x16x32_bf16(af[fm], bg, accg[fm][fn], 0, 0, 0);
                accu[fm][fn] = __builtin_amdgcn_mfma_f32_16x16x32_bf16(af[fm], bu, accu[fm][fn], 0, 0, 0);
            }
        }
    }

    // epilogue: silu(g)*u -> bf16 h_mid   (C/D: row=(lane>>4)*4+reg, col=lane&15)
#pragma unroll
    for (int fm = 0; fm < 4; ++fm)
#pragma unroll
        for (int fn = 0; fn < 2; ++fn)
#pragma unroll
            for (int r = 0; r < 4; ++r) {
                int mloc = wm + fm * 16 + quad * 4 + r;
                int prow = mrow0 + mloc;
                if (prow < Me) {
                    int col = n0 + wn + fn * 16 + l16;
                    float g = accg[fm][fn][r], u = accu[fm][fn][r];
                    float h = g / (1.f + __expf(-g)) * u;
                    h_mid[(size_t)(off + prow) * IDIM + col] = f2bf(h);
                }
            }
}

// ---------------- down GEMM ----------------
// y_pair[pair, n] = h_mid[pair] . down_e[n],  bf16 out (weight applied in reduce)
__global__ __launch_bounds__(256, 2) void k_down(
    const unsigned short* __restrict__ h_mid, const float* __restrict__ down,
    const int* __restrict__ offsets, const int* __restrict__ mtb,
    unsigned short* __restrict__ y_pair)
{
    __shared__ short8 sA[512], sB[512];
    __shared__ int sInfo[4];
    int tid = threadIdx.x;
    if (tid == 0) {
        int mt = blockIdx.x;
        if (mt >= mtb[NEXP]) { sInfo[0] = -1; }
        else {
            int e = 0;
            while (mtb[e + 1] <= mt) e++;
            sInfo[0] = e; sInfo[1] = offsets[e];
            sInfo[2] = offsets[e + 1] - offsets[e];
            sInfo[3] = (mt - mtb[e]) * BM;
        }
    }
    __syncthreads();
    int e = sInfo[0];
    if (e < 0) return;
    int off = sInfo[1], Me = sInfo[2], mrow0 = sInfo[3];
    int n0 = blockIdx.y * 128;

    int hm = tid >> 1, half = tid & 1;
    int rowp = mrow0 + hm;
    int arow = off + ((rowp < Me) ? rowp : 0);
    const short8* aSrc = (const short8*)(h_mid + (size_t)arow * IDIM);
    const float4* bSrc = (const float4*)(down + ((size_t)e * HDIM + (n0 + hm)) * IDIM);
    int w0 = idx16(hm, half * 2);
    int w1 = w0 + 16;

    int wave = tid >> 6, lane = tid & 63, quad = lane >> 4, l16 = lane & 15;
    int wm = (wave & 1) * 64, wn = (wave >> 1) * 64;
    int aBase = ((wm >> 4) * 4 + quad) * 16 + l16;
    int bBase = ((wn >> 4) * 4 + quad) * 16 + l16;

    f32x4 zero = {0.f, 0.f, 0.f, 0.f};
    f32x4 acc[4][4];
#pragma unroll
    for (int i = 0; i < 4; ++i)
#pragma unroll
        for (int j = 0; j < 4; ++j) acc[i][j] = zero;

    for (int k0 = 0; k0 < IDIM; k0 += BK) {
        int abase = (k0 >> 3) + (half << 1);
        short8 A0 = aSrc[abase], A1 = aSrc[abase + 1];
        int bbase = (k0 >> 2) + (half << 2);
        float4 b0 = bSrc[bbase], b1 = bSrc[bbase + 1], b2 = bSrc[bbase + 2], b3 = bSrc[bbase + 3];
        __syncthreads();
        sA[w0] = A0; sA[w1] = A1;
        sB[w0] = pack8(b0, b1); sB[w1] = pack8(b2, b3);
        __syncthreads();
        short8 af[4];
#pragma unroll
        for (int fm = 0; fm < 4; ++fm) af[fm] = sA[aBase + fm * 64];
#pragma unroll
        for (int fn = 0; fn < 4; ++fn) {
            short8 bf = sB[bBase + fn * 64];
#pragma unroll
            for (int fm = 0; fm < 4; ++fm)
                acc[fm][fn] = __builtin_amdgcn_mfma_f32_16x16x32_bf16(af[fm], bf, acc[fm][fn], 0, 0, 0);
        }
    }

#pragma unroll
    for (int fm = 0; fm < 4; ++fm)
#pragma unroll
        for (int fn = 0; fn < 4; ++fn)
#pragma unroll
            for (int r = 0; r < 4; ++r) {
                int mloc = wm + fm * 16 + quad * 4 + r;
                int prow = mrow0 + mloc;
                if (prow < Me) {
                    int col = n0 + wn + fn * 16 + l16;
                    y_pair[(size_t)(off + prow) * HDIM + col] = f2bf(acc[fm][fn][r]);
                }
            }
}

// ---------------- per-token weighted reduce ----------------
__global__ void k_reduce(const unsigned short* __restrict__ y_pair,
                         const int* __restrict__ pair_slot,
                         const float* __restrict__ topw, float* __restrict__ out)
{
    int t = blockIdx.x;
    __shared__ int ss[TOPK];
    __shared__ float sw[TOPK];
    if (threadIdx.x < TOPK) {
        ss[threadIdx.x] = pair_slot[t * TOPK + threadIdx.x];
        sw[threadIdx.x] = topw[t * TOPK + threadIdx.x];
    }
    __syncthreads();
    int c = threadIdx.x * 4;
    float a0 = 0.f, a1 = 0.f, a2 = 0.f, a3 = 0.f;
    for (int k = 0; k < TOPK; ++k) {
        const unsigned short* yr = y_pair + (size_t)ss[k] * HDIM + c;
        uint2 v = *(const uint2*)yr;
        float w = sw[k];
        a0 += w * bf2f((unsigned short)(v.x & 0xffff));
        a1 += w * bf2f((unsigned short)(v.x >> 16));
        a2 += w * bf2f((unsigned short)(v.y & 0xffff));
        a3 += w * bf2f((unsigned short)(v.y >> 16));
    }
    float4 o = {a0, a1, a2, a3};
    *(float4*)(out + (size_t)t * HDIM + c) = o;
}

extern "C" void kernel_launch(void* const* d_in, const int* in_sizes, int n_in,
                              void* d_out, int out_size, void* d_ws, size_t ws_size,
                              hipStream_t stream) {
    (void)in_sizes; (void)n_in; (void)out_size; (void)ws_size;
    const float* hidden = (const float*)d_in[0];
    const int*   tki    = (const int*)d_in[1];
    const float* tkw    = (const float*)d_in[2];
    const float* gate   = (const float*)d_in[3];
    const float* up     = (const float*)d_in[4];
    const float* down   = (const float*)d_in[5];
    float* out = (float*)d_out;

    char* w = (char*)d_ws;
    unsigned short* h_mid  = (unsigned short*)w;                                   // NPAIR*IDIM bf16 = 25.2 MB
    unsigned short* y_pair = (unsigned short*)(w + (size_t)NPAIR * IDIM * 2);      // NPAIR*HDIM bf16 = 33.6 MB
    int* ib = (int*)(w + (size_t)NPAIR * IDIM * 2 + (size_t)NPAIR * HDIM * 2);
    int* pair_token = ib;                // NPAIR
    int* pair_slot  = ib + NPAIR;        // NPAIR
    int* counts     = ib + 2 * NPAIR;    // NEXP
    int* cursor     = counts + NEXP;     // NEXP
    int* offsets    = cursor + NEXP;     // NEXP+1
    int* mtb        = offsets + NEXP + 1;// NEXP+1

    k_init<<<1, 64, 0, stream>>>(counts);
    k_hist<<<NPAIR / 256, 256, 0, stream>>>(tki, counts);
    k_scan<<<1, 64, 0, stream>>>(counts, offsets, mtb, cursor);
    k_scatter<<<NPAIR / 256, 256, 0, stream>>>(tki, cursor, offsets, pair_token, pair_slot);
    k_gateup<<<dim3(MT_MAX, IDIM / 64), 256, 0, stream>>>(hidden, gate, up, pair_token, offsets, mtb, h_mid);
    k_down<<<dim3(MT_MAX, HDIM / 128), 256, 0, stream>>>(h_mid, down, offsets, mtb, y_pair);
    k_reduce<<<T_TOK, 256, 0, stream>>>(y_pair, pair_slot, tkw, out);
}